// Round 1
// baseline (169.194 us; speedup 1.0000x reference)
//
#include <hip/hip_runtime.h>

#define S_LEN 2048
#define DHEAD 64
#define BQ 64
#define BK 64

typedef float f32x4 __attribute__((ext_vector_type(4)));
typedef __bf16 bf16x8 __attribute__((ext_vector_type(8)));
typedef unsigned short u16x8 __attribute__((ext_vector_type(8)));
typedef unsigned short u16x4 __attribute__((ext_vector_type(4)));

static __device__ __forceinline__ unsigned short f2bf(float f) {
    unsigned int x = __builtin_bit_cast(unsigned int, f);
    unsigned int r = (x + 0x7fffu + ((x >> 16) & 1u)) >> 16;
    return (unsigned short)r;
}

// byte offset into a [64][64]-bf16 LDS tile (128B rows) with XOR swizzle
static __device__ __forceinline__ int swz(int row, int cb) {
    return row * 128 + (cb ^ ((row & 7) << 4));
}

__global__ __launch_bounds__(256)
void attn_fwd(const float* __restrict__ Qg, const float* __restrict__ Kg,
              const float* __restrict__ Vg, float* __restrict__ Og) {
    __shared__ __align__(16) unsigned short sK[64 * 64];
    __shared__ __align__(16) unsigned short sV[64 * 64]; // transposed: [d][k]
    __shared__ __align__(16) unsigned short sP[64 * 64];

    const int tid  = threadIdx.x;
    const int lane = tid & 63;
    const int w    = tid >> 6;          // wave 0..3, owns q rows [w*16, w*16+16)
    const int blk_q = blockIdx.x;       // 0..31
    const int bh    = blockIdx.y;       // 0..31
    const int q0    = blk_q * BQ;

    const size_t base = (size_t)bh * S_LEN * DHEAD;

    const int col_c = lane & 15;        // MFMA C col / A row / B col
    const int row_c = (lane >> 4) * 4;  // MFMA C row base (+reg)
    const int dfrag = (lane >> 4) * 8;  // MFMA A/B k-offset

    // ---- Q fragments, scaled by 1/sqrt(D)=1/8, held in registers ----
    bf16x8 aq[2];
    {
        const int qrow = q0 + w * 16 + col_c;
        const float* qp = Qg + base + (size_t)qrow * DHEAD;
#pragma unroll
        for (int kk = 0; kk < 2; ++kk) {
            const float* p = qp + kk * 32 + dfrag;
            f32x4 a = *(const f32x4*)(p);
            f32x4 b = *(const f32x4*)(p + 4);
            u16x8 t;
#pragma unroll
            for (int j = 0; j < 4; ++j) {
                t[j]     = f2bf(a[j] * 0.125f);
                t[4 + j] = f2bf(b[j] * 0.125f);
            }
            aq[kk] = __builtin_bit_cast(bf16x8, t);
        }
    }

    f32x4 o[4];
#pragma unroll
    for (int dn = 0; dn < 4; ++dn) o[dn] = (f32x4){0.f, 0.f, 0.f, 0.f};
    float m_run[4], l_run[4];
#pragma unroll
    for (int r = 0; r < 4; ++r) { m_run[r] = -INFINITY; l_run[r] = 0.f; }

    for (int kt = 0; kt <= blk_q; ++kt) {
        // ---- stage K tile: row-major bf16, swizzled ----
        {
            const int r  = tid >> 2;
            const int c0 = (tid & 3) * 16;
            const float* kp = Kg + base + (size_t)(kt * BK + r) * DHEAD + c0;
            f32x4 k0 = *(const f32x4*)(kp);
            f32x4 k1 = *(const f32x4*)(kp + 4);
            f32x4 k2 = *(const f32x4*)(kp + 8);
            f32x4 k3 = *(const f32x4*)(kp + 12);
            u16x8 p0, p1;
#pragma unroll
            for (int j = 0; j < 4; ++j) {
                p0[j]     = f2bf(k0[j]);
                p0[4 + j] = f2bf(k1[j]);
                p1[j]     = f2bf(k2[j]);
                p1[4 + j] = f2bf(k3[j]);
            }
            *(u16x8*)((char*)sK + swz(r, c0 * 2))      = p0;
            *(u16x8*)((char*)sK + swz(r, c0 * 2 + 16)) = p1;
        }
        // ---- stage V tile transposed: sV[d][k], swizzled ----
        {
            const int kb = (tid >> 4) * 4;
            const int db = (tid & 15) * 4;
            const float* vp = Vg + base + (size_t)(kt * BK + kb) * DHEAD + db;
            f32x4 v0 = *(const f32x4*)(vp);
            f32x4 v1 = *(const f32x4*)(vp + DHEAD);
            f32x4 v2 = *(const f32x4*)(vp + 2 * DHEAD);
            f32x4 v3 = *(const f32x4*)(vp + 3 * DHEAD);
#pragma unroll
            for (int j = 0; j < 4; ++j) {
                u16x4 t;
                t[0] = f2bf(v0[j]); t[1] = f2bf(v1[j]);
                t[2] = f2bf(v2[j]); t[3] = f2bf(v3[j]);
                *(u16x4*)((char*)sV + swz(db + j, kb * 2)) = t;
            }
        }
        __syncthreads();

        // ---- S = Q K^T  (per wave: 16 q-rows x 64 k-cols) ----
        f32x4 s[4];
#pragma unroll
        for (int n = 0; n < 4; ++n) {
            f32x4 acc = (f32x4){0.f, 0.f, 0.f, 0.f};
#pragma unroll
            for (int kk = 0; kk < 2; ++kk) {
                u16x8 braw = *(const u16x8*)((char*)sK +
                               swz(n * 16 + col_c, (kk * 32 + dfrag) * 2));
                acc = __builtin_amdgcn_mfma_f32_16x16x32_bf16(
                        aq[kk], __builtin_bit_cast(bf16x8, braw), acc, 0, 0, 0);
            }
            s[n] = acc;
        }

        // ---- causal mask (diagonal tile only) ----
        if (kt == blk_q) {
#pragma unroll
            for (int n = 0; n < 4; ++n) {
                const int kg = kt * BK + n * 16 + col_c;
#pragma unroll
                for (int r = 0; r < 4; ++r) {
                    const int qg = q0 + w * 16 + row_c + r;
                    if (kg > qg) s[n][r] = -INFINITY;
                }
            }
        }

        // ---- online softmax ----
#pragma unroll
        for (int r = 0; r < 4; ++r) {
            float v = fmaxf(fmaxf(s[0][r], s[1][r]), fmaxf(s[2][r], s[3][r]));
            v = fmaxf(v, __shfl_xor(v, 1));
            v = fmaxf(v, __shfl_xor(v, 2));
            v = fmaxf(v, __shfl_xor(v, 4));
            v = fmaxf(v, __shfl_xor(v, 8));
            const float mn = fmaxf(m_run[r], v);
            const float alpha = __expf(m_run[r] - mn);   // -inf start -> 0
            m_run[r] = mn;
            float rs = 0.f;
#pragma unroll
            for (int n = 0; n < 4; ++n) {
                float p = __expf(s[n][r] - mn);
                s[n][r] = p;
                rs += p;
            }
            rs += __shfl_xor(rs, 1);
            rs += __shfl_xor(rs, 2);
            rs += __shfl_xor(rs, 4);
            rs += __shfl_xor(rs, 8);
            l_run[r] = l_run[r] * alpha + rs;
#pragma unroll
            for (int dn = 0; dn < 4; ++dn) o[dn][r] *= alpha;
        }

        // ---- P -> LDS (bf16) in A-fragment layout rows (per-wave region) ----
#pragma unroll
        for (int n = 0; n < 4; ++n)
#pragma unroll
            for (int r = 0; r < 4; ++r)
                *(unsigned short*)((char*)sP +
                    swz(w * 16 + row_c + r, (n * 16 + col_c) * 2)) = f2bf(s[n][r]);

        // ---- O += P V ----
        bf16x8 pa[2];
#pragma unroll
        for (int kk = 0; kk < 2; ++kk) {
            u16x8 t = *(const u16x8*)((char*)sP +
                        swz(w * 16 + col_c, (kk * 32 + dfrag) * 2));
            pa[kk] = __builtin_bit_cast(bf16x8, t);
        }
#pragma unroll
        for (int dn = 0; dn < 4; ++dn) {
#pragma unroll
            for (int kk = 0; kk < 2; ++kk) {
                u16x8 t = *(const u16x8*)((char*)sV +
                            swz(dn * 16 + col_c, (kk * 32 + dfrag) * 2));
                o[dn] = __builtin_amdgcn_mfma_f32_16x16x32_bf16(
                          pa[kk], __builtin_bit_cast(bf16x8, t), o[dn], 0, 0, 0);
            }
        }
        __syncthreads();   // protect sK/sV for next iteration
    }

    // ---- epilogue: divide by l, store fp32 ----
#pragma unroll
    for (int r = 0; r < 4; ++r) {
        const float inv = 1.0f / l_run[r];
        const int qg = q0 + w * 16 + row_c + r;
        float* op = Og + base + (size_t)qg * DHEAD + col_c;
#pragma unroll
        for (int dn = 0; dn < 4; ++dn)
            op[dn * 16] = o[dn][r] * inv;
    }
}

extern "C" void kernel_launch(void* const* d_in, const int* in_sizes, int n_in,
                              void* d_out, int out_size, void* d_ws, size_t ws_size,
                              hipStream_t stream) {
    const float* Q = (const float*)d_in[0];
    const float* K = (const float*)d_in[1];
    const float* V = (const float*)d_in[2];
    float* O = (float*)d_out;
    const int BH = in_sizes[0] / (S_LEN * DHEAD);   // = B*H = 32
    dim3 grid(S_LEN / BQ, BH);
    attn_fwd<<<grid, 256, 0, stream>>>(Q, K, V, O);
}

// Round 2
// 70.318 us; speedup vs baseline: 2.4061x; 2.4061x over previous
//
#include <hip/hip_runtime.h>

#define S_LEN 2048
#define DHEAD 64
#define BQ 64
#define BK 64
#define NBLKQ (S_LEN / BQ)   // 32
#define NBH 32               // B*H

typedef float f32x4 __attribute__((ext_vector_type(4)));
typedef __bf16 bf16x8 __attribute__((ext_vector_type(8)));
typedef unsigned short u16x8 __attribute__((ext_vector_type(8)));
typedef unsigned short u16x4 __attribute__((ext_vector_type(4)));

static __device__ __forceinline__ unsigned short bfr(float f) {
    return __builtin_bit_cast(unsigned short, (__bf16)f);
}
// byte offset into a [rows][64]-bf16 LDS tile (128B rows) with XOR swizzle
static __device__ __forceinline__ int swz(int row, int cb) {
    return row * 128 + (cb ^ ((row & 7) << 4));
}

__global__ __launch_bounds__(256)
void cvt_bf16(const float* __restrict__ src, unsigned short* __restrict__ dst, int n4) {
    const int stride = gridDim.x * blockDim.x;
    for (int i = blockIdx.x * blockDim.x + threadIdx.x; i < n4; i += stride) {
        f32x4 v = ((const f32x4*)src)[i];
        u16x4 t;
        t[0] = bfr(v[0]); t[1] = bfr(v[1]); t[2] = bfr(v[2]); t[3] = bfr(v[3]);
        ((u16x4*)dst)[i] = t;
    }
}

template<bool PRE>
__global__ __launch_bounds__(256)
void attn_fwd(const float* __restrict__ Qg,
              const float* __restrict__ K32, const float* __restrict__ V32,
              const unsigned short* __restrict__ Kb,
              const unsigned short* __restrict__ Vb,
              float* __restrict__ Og) {
    __shared__ __align__(16) unsigned short sK[2][BK * DHEAD];  // row-major, swizzled
    __shared__ __align__(16) unsigned short sV[2][DHEAD * BK];  // [d][k], swizzled
    __shared__ __align__(16) unsigned short sP[4][16 * BK];     // per-wave P^T [q][k]

    const int tid  = threadIdx.x;
    const int lane = tid & 63;
    const int w    = tid >> 6;
    // heavy-first: largest blk_q dispatched first (causal load balance)
    const int blk_q = (NBLKQ - 1) - ((int)blockIdx.x >> 5);
    const int bh    = (int)blockIdx.x & (NBH - 1);
    const int q0    = blk_q * BQ;
    const size_t base = (size_t)bh * (S_LEN * DHEAD);

    const int col = lane & 15;   // this lane's q (within wave tile) / MFMA n
    const int hi  = lane >> 4;

    // V staging indices (both paths)
    const int vkb = (tid >> 4) * 4;
    const int vdb = (tid & 15) * 4;
    // fallback K staging indices
    const int fkr = tid >> 2;
    const int fkc = (tid & 3) * 16;

    u16x4 vregs[4];
    f32x4 kr32[4], vr32[4];

    auto stage_issue = [&](int buf, int kt) {
        if constexpr (PRE) {
            // K: direct-to-LDS DMA, source pre-swizzled so swizzled reads work
#pragma unroll
            for (int i = 0; i < 2; ++i) {
                const int row = w * 8 + i * 32 + (lane >> 3);
                const int ch  = (lane & 7) ^ (lane >> 3);   // = (lane&7) ^ (row&7)
                const unsigned short* gp =
                    Kb + base + (size_t)(kt * BK + row) * DHEAD + ch * 8;
                __builtin_amdgcn_global_load_lds(
                    (const __attribute__((address_space(1))) unsigned int*)gp,
                    (__attribute__((address_space(3))) unsigned int*)&sK[buf][w * 512 + i * 2048],
                    16, 0, 0);
            }
            const unsigned short* vp =
                Vb + base + (size_t)(kt * BK + vkb) * DHEAD + vdb;
#pragma unroll
            for (int j = 0; j < 4; ++j)
                vregs[j] = *(const u16x4*)(vp + j * DHEAD);
        } else {
            const float* kp = K32 + base + (size_t)(kt * BK + fkr) * DHEAD + fkc;
#pragma unroll
            for (int j = 0; j < 4; ++j) kr32[j] = *(const f32x4*)(kp + j * 4);
            const float* vp = V32 + base + (size_t)(kt * BK + vkb) * DHEAD + vdb;
#pragma unroll
            for (int j = 0; j < 4; ++j) vr32[j] = *(const f32x4*)(vp + j * DHEAD);
        }
    };

    auto stage_write = [&](int buf) {
        char* sVb_ = (char*)&sV[buf][0];
        if constexpr (PRE) {
#pragma unroll
            for (int dd = 0; dd < 4; ++dd) {       // transpose V in registers
                u16x4 t;
#pragma unroll
                for (int j = 0; j < 4; ++j) t[j] = vregs[j][dd];
                *(u16x4*)(sVb_ + swz(vdb + dd, vkb * 2)) = t;
            }
        } else {
            char* sKb_ = (char*)&sK[buf][0];
            u16x8 p0, p1;
#pragma unroll
            for (int j = 0; j < 4; ++j) {
                p0[j] = bfr(kr32[0][j]); p0[4 + j] = bfr(kr32[1][j]);
                p1[j] = bfr(kr32[2][j]); p1[4 + j] = bfr(kr32[3][j]);
            }
            *(u16x8*)(sKb_ + swz(fkr, fkc * 2))      = p0;
            *(u16x8*)(sKb_ + swz(fkr, fkc * 2 + 16)) = p1;
#pragma unroll
            for (int dd = 0; dd < 4; ++dd) {
                u16x4 t;
#pragma unroll
                for (int j = 0; j < 4; ++j) t[j] = bfr(vr32[j][dd]);
                *(u16x4*)(sVb_ + swz(vdb + dd, vkb * 2)) = t;
            }
        }
    };

    // ---- Q fragment (B-operand of swapped QK^T), scaled by 1/sqrt(D) ----
    bf16x8 qf[2];
    {
        const int qrow = q0 + w * 16 + col;
        const float* qp = Qg + base + (size_t)qrow * DHEAD + hi * 8;
#pragma unroll
        for (int kk = 0; kk < 2; ++kk) {
            f32x4 a = *(const f32x4*)(qp + kk * 32);
            f32x4 b = *(const f32x4*)(qp + kk * 32 + 4);
            u16x8 t;
#pragma unroll
            for (int j = 0; j < 4; ++j) {
                t[j]     = bfr(a[j] * 0.125f);
                t[4 + j] = bfr(b[j] * 0.125f);
            }
            qf[kk] = __builtin_bit_cast(bf16x8, t);
        }
    }

    // ---- precomputed swizzled LDS byte offsets (all compile-time indexed) ----
    int offAB[4][2];
#pragma unroll
    for (int n = 0; n < 4; ++n)
#pragma unroll
        for (int kk = 0; kk < 2; ++kk)
            offAB[n][kk] = swz(n * 16 + col, (kk * 32 + hi * 8) * 2);
    char* sPw = (char*)&sP[w][0];
    int offPS[4], offPL[2];
#pragma unroll
    for (int n = 0; n < 4; ++n)
        offPS[n] = col * 128 + ((n * 32 + hi * 8) ^ ((col & 7) << 4));
#pragma unroll
    for (int kk = 0; kk < 2; ++kk)
        offPL[kk] = col * 128 + ((kk * 64 + hi * 16) ^ ((col & 7) << 4));

    f32x4 o[4];
#pragma unroll
    for (int dn = 0; dn < 4; ++dn) o[dn] = (f32x4){0.f, 0.f, 0.f, 0.f};
    float m_run = -INFINITY, l_run = 0.f;

    stage_issue(0, 0);
    stage_write(0);
    __syncthreads();

    int cur = 0;
    for (int kt = 0; kt <= blk_q; ++kt) {
        char* sKc = (char*)&sK[0][0] + cur * (BK * DHEAD * 2);
        char* sVc = (char*)&sV[0][0] + cur * (DHEAD * BK * 2);

        if (kt < blk_q) stage_issue(cur ^ 1, kt + 1);   // issue-early (T14)

        // ---- S^T = K Q^T : lane owns q=col, k = n*16 + hi*4 + r ----
        f32x4 st[4];
#pragma unroll
        for (int n = 0; n < 4; ++n) {
            f32x4 acc = (f32x4){0.f, 0.f, 0.f, 0.f};
#pragma unroll
            for (int kk = 0; kk < 2; ++kk) {
                u16x8 kf = *(const u16x8*)(sKc + offAB[n][kk]);
                acc = __builtin_amdgcn_mfma_f32_16x16x32_bf16(
                        __builtin_bit_cast(bf16x8, kf), qf[kk], acc, 0, 0, 0);
            }
            st[n] = acc;
        }

        // ---- causal mask (diagonal tile only) ----
        if (kt == blk_q) {
            const int qg = q0 + w * 16 + col;
#pragma unroll
            for (int n = 0; n < 4; ++n)
#pragma unroll
                for (int r = 0; r < 4; ++r)
                    if (kt * BK + n * 16 + hi * 4 + r > qg) st[n][r] = -INFINITY;
        }

        // ---- per-lane online softmax (one q per lane) ----
        float mx = st[0][0];
#pragma unroll
        for (int n = 0; n < 4; ++n)
#pragma unroll
            for (int r = 0; r < 4; ++r) mx = fmaxf(mx, st[n][r]);
        mx = fmaxf(mx, __shfl_xor(mx, 16));
        mx = fmaxf(mx, __shfl_xor(mx, 32));
        const float mn    = fmaxf(m_run, mx);
        const float alpha = __expf(m_run - mn);
        m_run = mn;
        float sum = 0.f;
#pragma unroll
        for (int n = 0; n < 4; ++n)
#pragma unroll
            for (int r = 0; r < 4; ++r) {
                float p = __expf(st[n][r] - mn);
                st[n][r] = p;
                sum += p;
            }
        sum += __shfl_xor(sum, 16);
        sum += __shfl_xor(sum, 32);
        l_run = l_run * alpha + sum;
#pragma unroll
        for (int dn = 0; dn < 4; ++dn) o[dn] *= alpha;

        // ---- P^T -> per-wave LDS (vectorized 8B stores) ----
#pragma unroll
        for (int n = 0; n < 4; ++n) {
            u16x4 t;
#pragma unroll
            for (int r = 0; r < 4; ++r) t[r] = bfr(st[n][r]);
            *(u16x4*)(sPw + offPS[n]) = t;
        }

        // ---- O^T += V^T P^T ----
        bf16x8 pb[2];
#pragma unroll
        for (int kk = 0; kk < 2; ++kk)
            pb[kk] = __builtin_bit_cast(bf16x8, *(const u16x8*)(sPw + offPL[kk]));
#pragma unroll
        for (int dn = 0; dn < 4; ++dn)
#pragma unroll
            for (int kk = 0; kk < 2; ++kk) {
                u16x8 vf = *(const u16x8*)(sVc + offAB[dn][kk]);
                o[dn] = __builtin_amdgcn_mfma_f32_16x16x32_bf16(
                          __builtin_bit_cast(bf16x8, vf), pb[kk], o[dn], 0, 0, 0);
            }

        if (kt < blk_q) stage_write(cur ^ 1);   // write-late (V regs -> LDS)
        __syncthreads();
        cur ^= 1;
    }

    // ---- epilogue: O[q][d], vectorized f32x4 stores ----
    const float inv = 1.0f / l_run;
    const int qg = q0 + w * 16 + col;
    float* op = Og + base + (size_t)qg * DHEAD + hi * 4;
#pragma unroll
    for (int dn = 0; dn < 4; ++dn) {
        f32x4 t = o[dn] * inv;
        *(f32x4*)(op + dn * 16) = t;
    }
}

extern "C" void kernel_launch(void* const* d_in, const int* in_sizes, int n_in,
                              void* d_out, int out_size, void* d_ws, size_t ws_size,
                              hipStream_t stream) {
    const float* Q = (const float*)d_in[0];
    const float* K = (const float*)d_in[1];
    const float* V = (const float*)d_in[2];
    float* O = (float*)d_out;

    const size_t nelem = (size_t)NBH * S_LEN * DHEAD;   // 4,194,304
    const bool pre = ws_size >= 2 * nelem * sizeof(unsigned short);

    dim3 grid(NBLKQ * NBH);
    if (pre) {
        unsigned short* Kb = (unsigned short*)d_ws;
        unsigned short* Vb = Kb + nelem;
        const int n4 = (int)(nelem / 4);
        cvt_bf16<<<4096, 256, 0, stream>>>(K, Kb, n4);
        cvt_bf16<<<4096, 256, 0, stream>>>(V, Vb, n4);
        attn_fwd<true><<<grid, 256, 0, stream>>>(Q, nullptr, nullptr, Kb, Vb, O);
    } else {
        attn_fwd<false><<<grid, 256, 0, stream>>>(Q, K, V, nullptr, nullptr, O);
    }
}

// Round 3
// 63.528 us; speedup vs baseline: 2.6633x; 1.1069x over previous
//
#include <hip/hip_runtime.h>

#define S_LEN 2048
#define DHEAD 64
#define BQ 64
#define BK 64
#define NBLKQ (S_LEN / BQ)   // 32
#define NBH 32               // B*H
#define QSCALE 0.18033688011112042f  // (1/8) * log2(e)
#define THR 8.0f

typedef float f32x4 __attribute__((ext_vector_type(4)));
typedef __bf16 bf16x8 __attribute__((ext_vector_type(8)));
typedef unsigned short u16x8 __attribute__((ext_vector_type(8)));
typedef unsigned short u16x4 __attribute__((ext_vector_type(4)));

static __device__ __forceinline__ unsigned short bfr(float f) {
    return __builtin_bit_cast(unsigned short, (__bf16)f);
}
// byte offset into a [rows][64]-bf16 LDS tile (128B rows) with XOR swizzle
static __device__ __forceinline__ int swz(int row, int cb) {
    return row * 128 + (cb ^ ((row & 7) << 4));
}

// ---- prepass: K fp32 -> bf16 elementwise ----
__global__ __launch_bounds__(256)
void cvt_bf16(const float* __restrict__ src, unsigned short* __restrict__ dst, int n4) {
    const int stride = gridDim.x * blockDim.x;
    for (int i = blockIdx.x * blockDim.x + threadIdx.x; i < n4; i += stride) {
        f32x4 v = ((const f32x4*)src)[i];
        u16x4 t;
        t[0] = bfr(v[0]); t[1] = bfr(v[1]); t[2] = bfr(v[2]); t[3] = bfr(v[3]);
        ((u16x4*)dst)[i] = t;
    }
}

// ---- prepass: V fp32 [bh][s][d] -> Vt bf16 [bh][d][s] ----
__global__ __launch_bounds__(256)
void cvt_transpose_v(const float* __restrict__ V, unsigned short* __restrict__ Vt) {
    __shared__ unsigned short t2[64][72];   // +8 pad breaks column-read conflicts
    const int bh = (int)blockIdx.x >> 5;
    const int st = (int)blockIdx.x & 31;
    const int t  = threadIdx.x;
    {
        const int sl = t >> 2, d0 = (t & 3) * 16;
        const float* src = V + ((size_t)bh * S_LEN + st * 64 + sl) * DHEAD + d0;
#pragma unroll
        for (int j = 0; j < 4; ++j) {
            f32x4 v = *(const f32x4*)(src + j * 4);
#pragma unroll
            for (int e = 0; e < 4; ++e) t2[sl][d0 + j * 4 + e] = bfr(v[e]);
        }
    }
    __syncthreads();
    const int d = t >> 2, sc = (t & 3) * 16;
    u16x8 a, b;
#pragma unroll
    for (int r = 0; r < 8; ++r) { a[r] = t2[sc + r][d]; b[r] = t2[sc + 8 + r][d]; }
    unsigned short* dst = Vt + ((size_t)bh * DHEAD + d) * S_LEN + st * 64 + sc;
    *(u16x8*)dst = a;
    *(u16x8*)(dst + 8) = b;
}

// ---- main kernel: K and V^T both staged by pure DMA ----
__global__ __launch_bounds__(256)
void attn_pre(const float* __restrict__ Qg,
              const unsigned short* __restrict__ Kb,
              const unsigned short* __restrict__ Vt,
              float* __restrict__ Og) {
    __shared__ __align__(16) unsigned short sK[2][BK * DHEAD];  // [k][d], swizzled
    __shared__ __align__(16) unsigned short sV[2][DHEAD * BK];  // [d][k], swizzled
    __shared__ __align__(16) unsigned short sP[4][16 * BK];     // per-wave P^T

    const int tid  = threadIdx.x;
    const int lane = tid & 63;
    const int w    = tid >> 6;
    const int blk_q = (NBLKQ - 1) - ((int)blockIdx.x >> 5);   // heavy-first
    const int bh    = (int)blockIdx.x & (NBH - 1);
    const int q0    = blk_q * BQ;
    const size_t base = (size_t)bh * (S_LEN * DHEAD);

    const int col = lane & 15;
    const int hi  = lane >> 4;

    const int srow = w * 8 + (lane >> 3);              // + i*32
    const int ch8  = ((lane & 7) ^ (lane >> 3)) * 8;   // pre-swizzled source col

    const unsigned short* Kbh = Kb + base;
    const unsigned short* Vth = Vt + base;

    auto issue = [&](int buf, int kt) {
#pragma unroll
        for (int i = 0; i < 2; ++i) {
            const int row = srow + i * 32;
            const unsigned short* gk = Kbh + (size_t)(kt * BK + row) * DHEAD + ch8;
            __builtin_amdgcn_global_load_lds(
                (const __attribute__((address_space(1))) unsigned int*)gk,
                (__attribute__((address_space(3))) unsigned int*)&sK[buf][w * 512 + i * 2048],
                16, 0, 0);
            const unsigned short* gv = Vth + (size_t)row * S_LEN + kt * BK + ch8;
            __builtin_amdgcn_global_load_lds(
                (const __attribute__((address_space(1))) unsigned int*)gv,
                (__attribute__((address_space(3))) unsigned int*)&sV[buf][w * 512 + i * 2048],
                16, 0, 0);
        }
    };

    // ---- Q fragment (B-operand of swapped QK^T), scaled by (1/8)*log2e ----
    bf16x8 qf[2];
    {
        const int qrow = q0 + w * 16 + col;
        const float* qp = Qg + base + (size_t)qrow * DHEAD + hi * 8;
#pragma unroll
        for (int kk = 0; kk < 2; ++kk) {
            f32x4 a = *(const f32x4*)(qp + kk * 32);
            f32x4 b = *(const f32x4*)(qp + kk * 32 + 4);
            u16x8 t;
#pragma unroll
            for (int j = 0; j < 4; ++j) {
                t[j]     = bfr(a[j] * QSCALE);
                t[4 + j] = bfr(b[j] * QSCALE);
            }
            qf[kk] = __builtin_bit_cast(bf16x8, t);
        }
    }

    // ---- precomputed swizzled LDS byte offsets ----
    int offAB[4][2];
#pragma unroll
    for (int n = 0; n < 4; ++n)
#pragma unroll
        for (int kk = 0; kk < 2; ++kk)
            offAB[n][kk] = swz(n * 16 + col, (kk * 32 + hi * 8) * 2);
    char* sPw = (char*)&sP[w][0];
    int offPS[4], offPL[2];
#pragma unroll
    for (int n = 0; n < 4; ++n)
        offPS[n] = col * 128 + ((n * 32 + hi * 8) ^ ((col & 7) << 4));
#pragma unroll
    for (int kk = 0; kk < 2; ++kk)
        offPL[kk] = col * 128 + ((kk * 64 + hi * 16) ^ ((col & 7) << 4));

    f32x4 o[4];
#pragma unroll
    for (int dn = 0; dn < 4; ++dn) o[dn] = (f32x4){0.f, 0.f, 0.f, 0.f};
    float m_run = -INFINITY, l_run = 0.f;

    issue(0, 0);
    int cur = 0;
    for (int kt = 0; kt <= blk_q; ++kt) {
        __syncthreads();                       // drains this tile's DMA, frees cur^1
        if (kt < blk_q) issue(cur ^ 1, kt + 1);

        const char* sKc = (const char*)&sK[cur][0];
        const char* sVc = (const char*)&sV[cur][0];

        // ---- S^T = K Q^T : lane owns q=col, k = n*16 + hi*4 + r ----
        f32x4 st[4];
#pragma unroll
        for (int n = 0; n < 4; ++n) {
            f32x4 acc = (f32x4){0.f, 0.f, 0.f, 0.f};
#pragma unroll
            for (int kk = 0; kk < 2; ++kk) {
                u16x8 kf = *(const u16x8*)(sKc + offAB[n][kk]);
                acc = __builtin_amdgcn_mfma_f32_16x16x32_bf16(
                        __builtin_bit_cast(bf16x8, kf), qf[kk], acc, 0, 0, 0);
            }
            st[n] = acc;
        }

        // ---- causal mask (diagonal tile only) ----
        if (kt == blk_q) {
            const int qg = q0 + w * 16 + col;
#pragma unroll
            for (int n = 0; n < 4; ++n)
#pragma unroll
                for (int r = 0; r < 4; ++r)
                    if (kt * BK + n * 16 + hi * 4 + r > qg) st[n][r] = -INFINITY;
        }

        // ---- per-lane online softmax in exp2 space, defer-max (T13) ----
        float mx = fmaxf(fmaxf(st[0][0], st[0][1]), fmaxf(st[0][2], st[0][3]));
#pragma unroll
        for (int n = 1; n < 4; ++n)
            mx = fmaxf(mx, fmaxf(fmaxf(st[n][0], st[n][1]), fmaxf(st[n][2], st[n][3])));
        mx = fmaxf(mx, __shfl_xor(mx, 16));
        mx = fmaxf(mx, __shfl_xor(mx, 32));
        if (!__all(mx <= m_run + THR)) {
            const float mn = fmaxf(m_run, mx);
            const float al = exp2f(m_run - mn);   // -inf start -> 0
            m_run = mn;
            l_run *= al;
#pragma unroll
            for (int dn = 0; dn < 4; ++dn) o[dn] *= al;
        }
        float sum = 0.f;
#pragma unroll
        for (int n = 0; n < 4; ++n)
#pragma unroll
            for (int r = 0; r < 4; ++r) {
                float p = exp2f(st[n][r] - m_run);
                st[n][r] = p;
                sum += p;
            }
        sum += __shfl_xor(sum, 16);
        sum += __shfl_xor(sum, 32);
        l_run += sum;

        // ---- P^T -> per-wave LDS (8B stores) ----
#pragma unroll
        for (int n = 0; n < 4; ++n) {
            u16x4 t;
#pragma unroll
            for (int r = 0; r < 4; ++r) t[r] = bfr(st[n][r]);
            *(u16x4*)(sPw + offPS[n]) = t;
        }

        // ---- O^T += V^T P^T ----
        bf16x8 pb[2];
#pragma unroll
        for (int kk = 0; kk < 2; ++kk)
            pb[kk] = __builtin_bit_cast(bf16x8, *(const u16x8*)(sPw + offPL[kk]));
#pragma unroll
        for (int dn = 0; dn < 4; ++dn)
#pragma unroll
            for (int kk = 0; kk < 2; ++kk) {
                u16x8 vf = *(const u16x8*)(sVc + offAB[dn][kk]);
                o[dn] = __builtin_amdgcn_mfma_f32_16x16x32_bf16(
                          __builtin_bit_cast(bf16x8, vf), pb[kk], o[dn], 0, 0, 0);
            }
        cur ^= 1;
    }

    // ---- epilogue ----
    const float inv = 1.0f / l_run;
    const int qg = q0 + w * 16 + col;
    float* op = Og + base + (size_t)qg * DHEAD + hi * 4;
#pragma unroll
    for (int dn = 0; dn < 4; ++dn) {
        f32x4 t = o[dn] * inv;
        *(f32x4*)(op + dn * 16) = t;
    }
}

// ---- fallback (no workspace): round-2 kernel, in-kernel conversion ----
__global__ __launch_bounds__(256)
void attn_fb(const float* __restrict__ Qg, const float* __restrict__ K32,
             const float* __restrict__ V32, float* __restrict__ Og) {
    __shared__ __align__(16) unsigned short sK[2][BK * DHEAD];
    __shared__ __align__(16) unsigned short sV[2][DHEAD * BK];
    __shared__ __align__(16) unsigned short sP[4][16 * BK];

    const int tid  = threadIdx.x;
    const int lane = tid & 63;
    const int w    = tid >> 6;
    const int blk_q = (NBLKQ - 1) - ((int)blockIdx.x >> 5);
    const int bh    = (int)blockIdx.x & (NBH - 1);
    const int q0    = blk_q * BQ;
    const size_t base = (size_t)bh * (S_LEN * DHEAD);

    const int col = lane & 15;
    const int hi  = lane >> 4;
    const int vkb = (tid >> 4) * 4;
    const int vdb = (tid & 15) * 4;
    const int fkr = tid >> 2;
    const int fkc = (tid & 3) * 16;

    f32x4 kr32[4], vr32[4];
    auto stage_issue = [&](int kt) {
        const float* kp = K32 + base + (size_t)(kt * BK + fkr) * DHEAD + fkc;
#pragma unroll
        for (int j = 0; j < 4; ++j) kr32[j] = *(const f32x4*)(kp + j * 4);
        const float* vp = V32 + base + (size_t)(kt * BK + vkb) * DHEAD + vdb;
#pragma unroll
        for (int j = 0; j < 4; ++j) vr32[j] = *(const f32x4*)(vp + j * DHEAD);
    };
    auto stage_write = [&](int buf) {
        char* sKb_ = (char*)&sK[buf][0];
        char* sVb_ = (char*)&sV[buf][0];
        u16x8 p0, p1;
#pragma unroll
        for (int j = 0; j < 4; ++j) {
            p0[j] = bfr(kr32[0][j]); p0[4 + j] = bfr(kr32[1][j]);
            p1[j] = bfr(kr32[2][j]); p1[4 + j] = bfr(kr32[3][j]);
        }
        *(u16x8*)(sKb_ + swz(fkr, fkc * 2))      = p0;
        *(u16x8*)(sKb_ + swz(fkr, fkc * 2 + 16)) = p1;
#pragma unroll
        for (int dd = 0; dd < 4; ++dd) {
            u16x4 t;
#pragma unroll
            for (int j = 0; j < 4; ++j) t[j] = bfr(vr32[j][dd]);
            *(u16x4*)(sVb_ + swz(vdb + dd, vkb * 2)) = t;
        }
    };

    bf16x8 qf[2];
    {
        const int qrow = q0 + w * 16 + col;
        const float* qp = Qg + base + (size_t)qrow * DHEAD + hi * 8;
#pragma unroll
        for (int kk = 0; kk < 2; ++kk) {
            f32x4 a = *(const f32x4*)(qp + kk * 32);
            f32x4 b = *(const f32x4*)(qp + kk * 32 + 4);
            u16x8 t;
#pragma unroll
            for (int j = 0; j < 4; ++j) {
                t[j]     = bfr(a[j] * QSCALE);
                t[4 + j] = bfr(b[j] * QSCALE);
            }
            qf[kk] = __builtin_bit_cast(bf16x8, t);
        }
    }

    int offAB[4][2];
#pragma unroll
    for (int n = 0; n < 4; ++n)
#pragma unroll
        for (int kk = 0; kk < 2; ++kk)
            offAB[n][kk] = swz(n * 16 + col, (kk * 32 + hi * 8) * 2);
    char* sPw = (char*)&sP[w][0];
    int offPS[4], offPL[2];
#pragma unroll
    for (int n = 0; n < 4; ++n)
        offPS[n] = col * 128 + ((n * 32 + hi * 8) ^ ((col & 7) << 4));
#pragma unroll
    for (int kk = 0; kk < 2; ++kk)
        offPL[kk] = col * 128 + ((kk * 64 + hi * 16) ^ ((col & 7) << 4));

    f32x4 o[4];
#pragma unroll
    for (int dn = 0; dn < 4; ++dn) o[dn] = (f32x4){0.f, 0.f, 0.f, 0.f};
    float m_run = -INFINITY, l_run = 0.f;

    stage_issue(0);
    stage_write(0);
    __syncthreads();

    int cur = 0;
    for (int kt = 0; kt <= blk_q; ++kt) {
        const char* sKc = (const char*)&sK[cur][0];
        const char* sVc = (const char*)&sV[cur][0];
        if (kt < blk_q) stage_issue(kt + 1);

        f32x4 st[4];
#pragma unroll
        for (int n = 0; n < 4; ++n) {
            f32x4 acc = (f32x4){0.f, 0.f, 0.f, 0.f};
#pragma unroll
            for (int kk = 0; kk < 2; ++kk) {
                u16x8 kf = *(const u16x8*)(sKc + offAB[n][kk]);
                acc = __builtin_amdgcn_mfma_f32_16x16x32_bf16(
                        __builtin_bit_cast(bf16x8, kf), qf[kk], acc, 0, 0, 0);
            }
            st[n] = acc;
        }
        if (kt == blk_q) {
            const int qg = q0 + w * 16 + col;
#pragma unroll
            for (int n = 0; n < 4; ++n)
#pragma unroll
                for (int r = 0; r < 4; ++r)
                    if (kt * BK + n * 16 + hi * 4 + r > qg) st[n][r] = -INFINITY;
        }
        float mx = fmaxf(fmaxf(st[0][0], st[0][1]), fmaxf(st[0][2], st[0][3]));
#pragma unroll
        for (int n = 1; n < 4; ++n)
            mx = fmaxf(mx, fmaxf(fmaxf(st[n][0], st[n][1]), fmaxf(st[n][2], st[n][3])));
        mx = fmaxf(mx, __shfl_xor(mx, 16));
        mx = fmaxf(mx, __shfl_xor(mx, 32));
        if (!__all(mx <= m_run + THR)) {
            const float mn = fmaxf(m_run, mx);
            const float al = exp2f(m_run - mn);
            m_run = mn;
            l_run *= al;
#pragma unroll
            for (int dn = 0; dn < 4; ++dn) o[dn] *= al;
        }
        float sum = 0.f;
#pragma unroll
        for (int n = 0; n < 4; ++n)
#pragma unroll
            for (int r = 0; r < 4; ++r) {
                float p = exp2f(st[n][r] - m_run);
                st[n][r] = p;
                sum += p;
            }
        sum += __shfl_xor(sum, 16);
        sum += __shfl_xor(sum, 32);
        l_run += sum;
#pragma unroll
        for (int n = 0; n < 4; ++n) {
            u16x4 t;
#pragma unroll
            for (int r = 0; r < 4; ++r) t[r] = bfr(st[n][r]);
            *(u16x4*)(sPw + offPS[n]) = t;
        }
        bf16x8 pb[2];
#pragma unroll
        for (int kk = 0; kk < 2; ++kk)
            pb[kk] = __builtin_bit_cast(bf16x8, *(const u16x8*)(sPw + offPL[kk]));
#pragma unroll
        for (int dn = 0; dn < 4; ++dn)
#pragma unroll
            for (int kk = 0; kk < 2; ++kk) {
                u16x8 vf = *(const u16x8*)(sVc + offAB[dn][kk]);
                o[dn] = __builtin_amdgcn_mfma_f32_16x16x32_bf16(
                          __builtin_bit_cast(bf16x8, vf), pb[kk], o[dn], 0, 0, 0);
            }
        if (kt < blk_q) stage_write(cur ^ 1);
        __syncthreads();
        cur ^= 1;
    }

    const float inv = 1.0f / l_run;
    const int qg = q0 + w * 16 + col;
    float* op = Og + base + (size_t)qg * DHEAD + hi * 4;
#pragma unroll
    for (int dn = 0; dn < 4; ++dn) {
        f32x4 t = o[dn] * inv;
        *(f32x4*)(op + dn * 16) = t;
    }
}

extern "C" void kernel_launch(void* const* d_in, const int* in_sizes, int n_in,
                              void* d_out, int out_size, void* d_ws, size_t ws_size,
                              hipStream_t stream) {
    const float* Q = (const float*)d_in[0];
    const float* K = (const float*)d_in[1];
    const float* V = (const float*)d_in[2];
    float* O = (float*)d_out;

    const size_t nelem = (size_t)NBH * S_LEN * DHEAD;   // 4,194,304
    const bool pre = ws_size >= 2 * nelem * sizeof(unsigned short);

    dim3 grid(NBLKQ * NBH);
    if (pre) {
        unsigned short* Kb = (unsigned short*)d_ws;
        unsigned short* Vt = Kb + nelem;
        cvt_bf16<<<2048, 256, 0, stream>>>(K, Kb, (int)(nelem / 4));
        cvt_transpose_v<<<NBH * (S_LEN / 64), 256, 0, stream>>>(V, Vt);
        attn_pre<<<grid, 256, 0, stream>>>(Q, Kb, Vt, O);
    } else {
        attn_fb<<<grid, 256, 0, stream>>>(Q, K, V, O);
    }
}